// Round 13
// baseline (393.324 us; speedup 1.0000x reference)
//
#include <hip/hip_runtime.h>

typedef __bf16 bf16x8 __attribute__((ext_vector_type(8)));
typedef float f32x4 __attribute__((ext_vector_type(4)));

__device__ __forceinline__ unsigned short f2bf(float f) {
    unsigned int u = __builtin_bit_cast(unsigned int, f);
    u += 0x7fffu + ((u >> 16) & 1u);
    return (unsigned short)(u >> 16);
}
__device__ __forceinline__ float bf2f(unsigned short u) {
    return __builtin_bit_cast(float, (unsigned)u << 16);
}

// XOR swizzle for 1024B-row LDS tiles: byte ^= ((row&7)<<4)
__device__ __forceinline__ unsigned swz1k(unsigned byte) {
    return byte ^ ((byte >> 6) & 0x70u);
}

// Raw barrier: LDS-visibility only; does NOT drain vmcnt.
__device__ __forceinline__ void bar_lgkm() {
    asm volatile("s_waitcnt lgkmcnt(0)\n\ts_barrier" ::: "memory");
}
#define SB() __builtin_amdgcn_sched_barrier(0)

// ---------------- K1: Pc[kc][j][t] = M[kc*32+t][j], M = Wq^T Wk  (bf16)
// plus Wv -> bf16 copy.
__global__ __launch_bounds__(256) void prep_kernel(
    const float* __restrict__ Wq, const float* __restrict__ Wk,
    const float* __restrict__ Wv, unsigned short* __restrict__ Pc,
    unsigned short* __restrict__ Wvb)
{
    int b = blockIdx.x;
    if (b < 1024) {
        int j0 = (b >> 4) * 8;
        int kc = b & 15;
        int jloc = threadIdx.x >> 5;
        int t = threadIdx.x & 31;
        int j = j0 + jloc, d = kc * 32 + t;
        float acc = 0.f;
        #pragma unroll 8
        for (int e = 0; e < 512; ++e)
            acc = fmaf(Wk[e * 512 + j], Wq[e * 512 + d], acc);
        Pc[((kc * 512) + j) * 32 + t] = f2bf(acc);
    } else {
        int i = (b - 1024) * 256 + (int)threadIdx.x;
        Wvb[i] = f2bf(Wv[i]);
    }
}

// issue H column-half h (64-row tile, 1024 threads): 4 float4/thread.
__device__ __forceinline__ void issue_h(int h, int tid, const float4* hsrc, float4 (&hh)[4]) {
    #pragma unroll
    for (int r = 0; r < 4; ++r) {
        int flat = r * 1024 + tid;         // [0,4096)
        hh[r] = hsrc[(flat >> 6) * 128 + h * 64 + (flat & 63)];
    }
}

// convert half h -> bf16 swizzled HBF (consumes hh)
__device__ __forceinline__ void convert_h(int h, int tid, char* HBF, float4 (&hh)[4]) {
    #pragma unroll
    for (int r = 0; r < 4; ++r) {
        int flat = r * 1024 + tid;
        int row = flat >> 6, ch = flat & 63;
        ushort4 bv;
        bv.x = f2bf(hh[r].x); bv.y = f2bf(hh[r].y);
        bv.z = f2bf(hh[r].z); bv.w = f2bf(hh[r].w);
        *(ushort4*)(HBF + swz1k((unsigned)row * 1024u + (unsigned)(h * 64 + ch) * 8u)) = bv;
    }
}

__device__ __forceinline__ void prime_pc(const unsigned short* bptr,
    bf16x8 (&st0)[2], bf16x8 (&st1)[2], bf16x8 (&st2)[2])
{
    #pragma unroll
    for (int jj = 0; jj < 2; ++jj) st0[jj] = *(const bf16x8*)(bptr + 0 * 16384 + jj * 512);
    #pragma unroll
    for (int jj = 0; jj < 2; ++jj) st1[jj] = *(const bf16x8*)(bptr + 1 * 16384 + jj * 512);
    #pragma unroll
    for (int jj = 0; jj < 2; ++jj) st2[jj] = *(const bf16x8*)(bptr + 2 * 16384 + jj * 512);
}

// 8-kc GEMM, 3-deep rolling Pc prefetch, NO H-issues inside (keeps the Pc
// consume stream free of in-order HBM pollution).
__device__ __forceinline__ void gemm8(
    int kcbase, int rl, int kg,
    const unsigned short* bptr, char* HBF,
    bf16x8 (&st0)[2], bf16x8 (&st1)[2], bf16x8 (&st2)[2],
    f32x4 (&acc)[4][2])
{
    #pragma unroll
    for (int k = 0; k < 8; ++k) {
        const int kc = kcbase + k;
        bf16x8 bn[2];
        if (kc + 3 < 16) {
            #pragma unroll
            for (int jj = 0; jj < 2; ++jj)
                bn[jj] = *(const bf16x8*)(bptr + (kc + 3) * 16384 + jj * 512);
        }
        bf16x8 a[4];
        #pragma unroll
        for (int i = 0; i < 4; ++i) {
            unsigned off = (unsigned)(i * 16 + rl) * 1024u + (unsigned)kc * 64u + (unsigned)kg * 16u;
            a[i] = *(bf16x8*)(HBF + swz1k(off));
        }
        #pragma unroll
        for (int i = 0; i < 4; ++i)
            #pragma unroll
            for (int jj = 0; jj < 2; ++jj)
                acc[i][jj] = __builtin_amdgcn_mfma_f32_16x16x32_bf16(a[i], st0[jj], acc[i][jj], 0, 0, 0);
        #pragma unroll
        for (int jj = 0; jj < 2; ++jj) { st0[jj] = st1[jj]; st1[jj] = st2[jj]; st2[jj] = bn[jj]; }
    }
}

// ---------------- one 64-row tile (4 batches) of the 2-tile block.
// If PREF: in the phases window (Pc-free), issue next tile's H halves and
// next Pc primes, pinned with sched_barrier; consumed after ~3K cy of
// scores/pool/g work, so HBM latency is covered and no Pc consume follows.
template<bool PREF>
__device__ __forceinline__ void do_tile(
    long long gb0, int fb,
    float4 (&h0)[4], float4 (&h1)[4],
    float4 (&hn0)[4], float4 (&hn1)[4],
    bf16x8 (&st0)[2], bf16x8 (&st1)[2], bf16x8 (&st2)[2],
    const float4* hsrc_next, const unsigned short* bptr,
    const float* __restrict__ F,
    float* __restrict__ out, unsigned short* __restrict__ g_ws,
    char* HBF, char* TBF, float* wbuf, float* FL, float* LFL,
    int tid, int wv, int ln, int rl, int kg)
{
    f32x4 acc[4][2];
    #pragma unroll
    for (int i = 0; i < 4; ++i)
        #pragma unroll
        for (int jj = 0; jj < 2; ++jj)
            acc[i][jj] = f32x4{0.f, 0.f, 0.f, 0.f};

    convert_h(0, tid, HBF, h0);      // waits h0 only
    bar_lgkm();
    gemm8(0, rl, kg, bptr, HBF, st0, st1, st2, acc);   // Pc rolls kc3..10
    convert_h(1, tid, HBF, h1);      // waits h1 (+older Pc already consumed)
    bar_lgkm();
    gemm8(8, rl, kg, bptr, HBF, st0, st1, st2, acc);   // Pc rolls kc11..15

    // write T into TBF (C layout: col=lane&15, row=(lane>>4)*4+p)
    #pragma unroll
    for (int i = 0; i < 4; ++i)
        #pragma unroll
        for (int jj = 0; jj < 2; ++jj)
            #pragma unroll
            for (int p = 0; p < 4; ++p) {
                unsigned row = (unsigned)(i * 16 + kg * 4 + p);
                unsigned col = (unsigned)(wv * 32 + jj * 16 + rl);
                *(unsigned short*)(TBF + swz1k(row * 1024u + col * 2u)) = f2bf(acc[i][jj][p]);
            }
    bar_lgkm();   // TBF ready

    // ---- Pc-free window: issue next tile's H + primes (pinned)
    if (PREF) {
        SB();
        issue_h(0, tid, hsrc_next, hn0);
        issue_h(1, tid, hsrc_next, hn1);
        prime_pc(bptr, st0, st1, st2);
        SB();
    }

    // ---- phase 3: waves 0-3: scores+softmax+w ; waves 4-11: residual pool
    if (wv < 4) {
        f32x4 sc0 = f32x4{0.f,0.f,0.f,0.f}, sc1 = sc0, sc2 = sc0, sc3 = sc0;
        __builtin_amdgcn_s_setprio(1);
        #pragma unroll
        for (int kc = 0; kc < 16; ++kc) {
            unsigned off = (unsigned)(wv * 16 + rl) * 1024u + (unsigned)kc * 64u + (unsigned)kg * 16u;
            bf16x8 aT = *(bf16x8*)(TBF + swz1k(off));
            bf16x8 bH = *(bf16x8*)(HBF + swz1k(off));   // H rows as B == H^T
            if ((kc & 3) == 0) sc0 = __builtin_amdgcn_mfma_f32_16x16x32_bf16(aT, bH, sc0, 0, 0, 0);
            else if ((kc & 3) == 1) sc1 = __builtin_amdgcn_mfma_f32_16x16x32_bf16(aT, bH, sc1, 0, 0, 0);
            else if ((kc & 3) == 2) sc2 = __builtin_amdgcn_mfma_f32_16x16x32_bf16(aT, bH, sc2, 0, 0, 0);
            else sc3 = __builtin_amdgcn_mfma_f32_16x16x32_bf16(aT, bH, sc3, 0, 0, 0);
        }
        __builtin_amdgcn_s_setprio(0);
        f32x4 sc;
        #pragma unroll
        for (int p = 0; p < 4; ++p) sc[p] = (sc0[p] + sc1[p]) + (sc2[p] + sc3[p]);

        float bias = LFL[fb + wv * 16 + rl];
        float alpha[4];
        #pragma unroll
        for (int p = 0; p < 4; ++p) {
            float s = sc[p] * 0.044194173824159216f + bias;  // 1/sqrt(512)
            float m = s;
            m = fmaxf(m, __shfl_xor(m, 8));
            m = fmaxf(m, __shfl_xor(m, 4));
            m = fmaxf(m, __shfl_xor(m, 2));
            m = fmaxf(m, __shfl_xor(m, 1));
            float e = expf(s - m);
            float sum = e;
            sum += __shfl_xor(sum, 8);
            sum += __shfl_xor(sum, 4);
            sum += __shfl_xor(sum, 2);
            sum += __shfl_xor(sum, 1);
            alpha[p] = e / sum;
        }
        float part = 0.f;
        #pragma unroll
        for (int p = 0; p < 4; ++p) part += FL[fb + wv * 16 + kg * 4 + p] * alpha[p];
        part += __shfl_xor(part, 16);
        part += __shfl_xor(part, 32);
        if (ln < 16) wbuf[wv * 16 + ln] = part;
    } else if (wv < 12) {
        // residual F-pool: unit = (batch bb, d-half dh); lane covers 4 d
        int u = wv - 4;
        int bb = u >> 1, dh = u & 1;
        const long long Bg = gb0 + bb;
        int d0 = dh * 256 + ln * 4;
        float o[4];
        #pragma unroll
        for (int q = 0; q < 4; ++q) o[q] = 0.f;
        #pragma unroll
        for (int k = 0; k < 16; ++k) {
            unsigned off = (unsigned)(bb * 16 + k) * 1024u + (unsigned)d0 * 2u;
            ushort4 h = *(ushort4*)(HBF + swz1k(off));
            float fk = FL[fb + bb * 16 + k];
            o[0] = fmaf(fk, bf2f(h.x), o[0]); o[1] = fmaf(fk, bf2f(h.y), o[1]);
            o[2] = fmaf(fk, bf2f(h.z), o[2]); o[3] = fmaf(fk, bf2f(h.w), o[3]);
        }
        float4 oa; oa.x = o[0]; oa.y = o[1]; oa.z = o[2]; oa.w = o[3];
        *(float4*)(out + Bg * 512 + d0) = oa;
    }
    bar_lgkm();   // wbuf ready

    // ---- phase 4: g (bf16). 16 waves = 4 batches x 4 d-quarters, from LDS.
    {
        int bb = wv >> 2, q4 = wv & 3;
        const long long Bg = gb0 + bb;
        int d0 = q4 * 128 + ln * 2;
        float g0 = 0.f, g1 = 0.f;
        #pragma unroll
        for (int k = 0; k < 16; ++k) {
            unsigned off = (unsigned)(bb * 16 + k) * 1024u + (unsigned)d0 * 2u;
            ushort2 h = *(ushort2*)(HBF + swz1k(off));
            float wk = wbuf[bb * 16 + k];
            g0 = fmaf(wk, bf2f(h.x), g0); g1 = fmaf(wk, bf2f(h.y), g1);
        }
        ushort2 g2; g2.x = f2bf(g0); g2.y = f2bf(g1);
        *(ushort2*)(g_ws + Bg * 512 + d0) = g2;
    }
    bar_lgkm();   // HBF free for next tile's convert
}

// ---------------- K2: fused main kernel. 1 block = 8 batches = 2 tiles of
// 64 rows, 1024 threads (16 waves, 4/SIMD). Next tile's H issued in the
// Pc-free phases window (pinned); pure Pc-streaming GEMM inside tiles.
__global__ __launch_bounds__(1024, 4) void attn_main_kernel(
    const float* __restrict__ H, const float* __restrict__ F,
    const unsigned short* __restrict__ Pc,
    float* __restrict__ out, unsigned short* __restrict__ g_ws)
{
    extern __shared__ char smem[];
    char* HBF  = smem;                        // 64 rows x 1024B, swizzled (64 KB)
    char* TBF  = smem + 65536;                // 64 KB
    float* wbuf = (float*)(smem + 131072);    // [4][16]
    float* FL   = (float*)(smem + 131328);    // [128] (2 tiles)
    float* LFL  = (float*)(smem + 131840);    // [128]

    const int tid = threadIdx.x;
    const int wv = tid >> 6;                  // 0..15
    const int ln = tid & 63;
    const int rl = ln & 15;
    const int kg = ln >> 4;
    const int blk = blockIdx.x;
    const float4* hsrc0 = (const float4*)(H + (long long)blk * 128 * 512);
    const float4* hsrc1 = hsrc0 + 64 * 128;   // second 64-row tile

    float fval = 0.f;
    if (tid < 128) fval = F[blk * 128 + tid];

    float4 hA0[4], hA1[4], hB0[4], hB1[4];
    bf16x8 st0[2], st1[2], st2[2];

    // per-wave j-slice: j = wv*32 + jj*16 + rl, jj in {0,1}
    const unsigned short* bptr = Pc + ((wv * 32 + rl) * 32 + kg * 8);

    // prologue issue order: h0 < primes < h1 (younger never force-drained)
    issue_h(0, tid, hsrc0, hA0);
    SB();
    prime_pc(bptr, st0, st1, st2);
    SB();
    issue_h(1, tid, hsrc0, hA1);
    SB();

    if (tid < 128) {
        FL[tid] = fval;
        LFL[tid] = logf(fval + 1e-8f);
    }

    do_tile<true >((long long)blk * 8,     0,  hA0, hA1, hB0, hB1, st0, st1, st2,
                   hsrc1, bptr, F, out, g_ws, HBF, TBF, wbuf, FL, LFL, tid, wv, ln, rl, kg);
    do_tile<false>((long long)blk * 8 + 4, 64, hB0, hB1, hA0, hA1, st0, st1, st2,
                   hsrc1, bptr, F, out, g_ws, HBF, TBF, wbuf, FL, LFL, tid, wv, ln, rl, kg);
}

// ---------------- K3: out += g @ Wv^T   (8192x512 @ 512x512, bf16 MFMA)
__global__ __launch_bounds__(256) void out_gemm_kernel(
    const unsigned short* __restrict__ g_ws,
    const unsigned short* __restrict__ Wvb,
    float* __restrict__ out)
{
    extern __shared__ char smem[];  // 32 KB: 32 rows x 1024B, swizzled
    const int tid = threadIdx.x;
    const int wv = tid >> 6, ln = tid & 63;
    const int rl = ln & 15, kg = ln >> 4;
    const long long r0 = (long long)blockIdx.x * 32;
    {
        const uint4* src = (const uint4*)(g_ws + r0 * 512);
        #pragma unroll
        for (int q = 0; q < 8; ++q) {
            int idx = q * 256 + tid;
            *(uint4*)(smem + swz1k((unsigned)idx * 16u)) = src[idx];
        }
    }
    __syncthreads();
    f32x4 acc[2][8];
    #pragma unroll
    for (int i = 0; i < 2; ++i)
        #pragma unroll
        for (int jj = 0; jj < 8; ++jj)
            acc[i][jj] = f32x4{0.f, 0.f, 0.f, 0.f};
    for (int kc = 0; kc < 16; ++kc) {
        bf16x8 a[2];
        #pragma unroll
        for (int i = 0; i < 2; ++i) {
            unsigned off = (unsigned)(i * 16 + rl) * 1024u + (unsigned)kc * 64u + (unsigned)kg * 16u;
            a[i] = *(bf16x8*)(smem + swz1k(off));
        }
        bf16x8 bfr[8];
        #pragma unroll
        for (int jj = 0; jj < 8; ++jj) {
            int n = wv * 128 + jj * 16 + rl;
            bfr[jj] = *(const bf16x8*)(Wvb + n * 512 + kc * 32 + kg * 8);
        }
        #pragma unroll
        for (int i = 0; i < 2; ++i)
            #pragma unroll
            for (int jj = 0; jj < 8; ++jj)
                acc[i][jj] = __builtin_amdgcn_mfma_f32_16x16x32_bf16(a[i], bfr[jj], acc[i][jj], 0, 0, 0);
    }
    #pragma unroll
    for (int i = 0; i < 2; ++i)
        #pragma unroll
        for (int jj = 0; jj < 8; ++jj)
            #pragma unroll
            for (int p = 0; p < 4; ++p) {
                int row = i * 16 + kg * 4 + p;
                int col = wv * 128 + jj * 16 + rl;
                out[(r0 + row) * 512 + col] += acc[i][jj][p];
            }
}

extern "C" void kernel_launch(void* const* d_in, const int* in_sizes, int n_in,
                              void* d_out, int out_size, void* d_ws, size_t ws_size,
                              hipStream_t stream)
{
    const float* H  = (const float*)d_in[0];
    const float* F  = (const float*)d_in[1];
    const float* Wq = (const float*)d_in[2];
    const float* Wk = (const float*)d_in[3];
    const float* Wv = (const float*)d_in[4];
    float* out = (float*)d_out;

    unsigned short* Pc  = (unsigned short*)d_ws;       // 16*512*32   = 262144 bf16
    unsigned short* Wvb = Pc + 262144;                 // 512*512     = 262144 bf16
    unsigned short* g   = Wvb + 262144;                // 8192*512    = 4194304 bf16
    (void)in_sizes; (void)n_in; (void)out_size; (void)ws_size;

    prep_kernel<<<dim3(2048), dim3(256), 0, stream>>>(Wq, Wk, Wv, Pc, Wvb);
    attn_main_kernel<<<dim3(1024), dim3(1024), 132352, stream>>>(H, F, Pc, out, g);
    out_gemm_kernel<<<dim3(256), dim3(256), 32768, stream>>>(g, Wvb, out);
}

// Round 14
// 203.334 us; speedup vs baseline: 1.9344x; 1.9344x over previous
//
#include <hip/hip_runtime.h>

typedef __bf16 bf16x8 __attribute__((ext_vector_type(8)));
typedef float f32x4 __attribute__((ext_vector_type(4)));

__device__ __forceinline__ unsigned short f2bf(float f) {
    unsigned int u = __builtin_bit_cast(unsigned int, f);
    u += 0x7fffu + ((u >> 16) & 1u);
    return (unsigned short)(u >> 16);
}
__device__ __forceinline__ float bf2f(unsigned short u) {
    return __builtin_bit_cast(float, (unsigned)u << 16);
}

// XOR swizzle for 1024B-row LDS tiles: byte ^= ((row&7)<<4)
__device__ __forceinline__ unsigned swz1k(unsigned byte) {
    return byte ^ ((byte >> 6) & 0x70u);
}

// Raw barrier: LDS-visibility only; does NOT drain vmcnt.
__device__ __forceinline__ void bar_lgkm() {
    asm volatile("s_waitcnt lgkmcnt(0)\n\ts_barrier" ::: "memory");
}
#define SB() __builtin_amdgcn_sched_barrier(0)

// ---------------- K1: Pc[kc][j][t] = M[kc*32+t][j], M = Wq^T Wk  (bf16)
// plus Wv -> bf16 copy.
__global__ __launch_bounds__(256) void prep_kernel(
    const float* __restrict__ Wq, const float* __restrict__ Wk,
    const float* __restrict__ Wv, unsigned short* __restrict__ Pc,
    unsigned short* __restrict__ Wvb)
{
    int b = blockIdx.x;
    if (b < 1024) {
        int j0 = (b >> 4) * 8;
        int kc = b & 15;
        int jloc = threadIdx.x >> 5;
        int t = threadIdx.x & 31;
        int j = j0 + jloc, d = kc * 32 + t;
        float acc = 0.f;
        #pragma unroll 8
        for (int e = 0; e < 512; ++e)
            acc = fmaf(Wk[e * 512 + j], Wq[e * 512 + d], acc);
        Pc[((kc * 512) + j) * 32 + t] = f2bf(acc);
    } else {
        int i = (b - 1024) * 256 + (int)threadIdx.x;
        Wvb[i] = f2bf(Wv[i]);
    }
}

// issue H column-quarter q (64-row tile, 1024 threads): 2 float4/thread.
__device__ __forceinline__ void issue_q(int q, int tid, const float4* hsrc, float4 (&hq)[2]) {
    #pragma unroll
    for (int r = 0; r < 2; ++r) {
        int flat = r * 1024 + tid;         // [0,2048)
        hq[r] = hsrc[(flat >> 5) * 128 + q * 32 + (flat & 31)];
    }
}

// convert quarter q -> bf16 swizzled HBF (consumes hq)
__device__ __forceinline__ void convert_q(int q, int tid, char* HBF, float4 (&hq)[2]) {
    #pragma unroll
    for (int r = 0; r < 2; ++r) {
        int flat = r * 1024 + tid;
        int row = flat >> 5, ch = flat & 31;
        ushort4 bv;
        bv.x = f2bf(hq[r].x); bv.y = f2bf(hq[r].y);
        bv.z = f2bf(hq[r].z); bv.w = f2bf(hq[r].w);
        *(ushort4*)(HBF + swz1k((unsigned)row * 1024u + (unsigned)(q * 32 + ch) * 8u)) = bv;
    }
}

// GEMM over kc = kcbase..kcbase+3, 2-deep rolling Pc prefetch, per-wave
// j-slice of 32 cols (2 frags). If PREF: issue H quarter at k==1 AFTER that
// iter's Pc issue (same schedule as the r11 baseline).
template<bool PREF>
__device__ __forceinline__ void gemm_q(
    int kcbase, int tid, int rl, int kg,
    const unsigned short* bptr, char* HBF,
    bf16x8 (&st0)[2], bf16x8 (&st1)[2],
    f32x4 (&acc)[4][2],
    float4 (&hq)[2], const float4* hsrc, int hq_q)
{
    #pragma unroll
    for (int k = 0; k < 4; ++k) {
        const int kc = kcbase + k;
        bf16x8 bn[2];
        if (kc + 2 < 16) {
            #pragma unroll
            for (int jj = 0; jj < 2; ++jj)
                bn[jj] = *(const bf16x8*)(bptr + (kc + 2) * 16384 + jj * 512);
        }
        if (PREF && k == 1) {
            SB();
            issue_q(hq_q, tid, hsrc, hq);
            SB();
        }
        bf16x8 a[4];
        #pragma unroll
        for (int i = 0; i < 4; ++i) {
            unsigned off = (unsigned)(i * 16 + rl) * 1024u + (unsigned)kc * 64u + (unsigned)kg * 16u;
            a[i] = *(bf16x8*)(HBF + swz1k(off));
        }
        #pragma unroll
        for (int i = 0; i < 4; ++i)
            #pragma unroll
            for (int jj = 0; jj < 2; ++jj)
                acc[i][jj] = __builtin_amdgcn_mfma_f32_16x16x32_bf16(a[i], st0[jj], acc[i][jj], 0, 0, 0);
        #pragma unroll
        for (int jj = 0; jj < 2; ++jj) { st0[jj] = st1[jj]; st1[jj] = bn[jj]; }
    }
}

// ---------------- K2: fused main kernel. 1 block = 4 batches = 64 H rows,
// 1024 threads (16 waves, 4/SIMD). GEMM identical to the r11 baseline;
// phases fully wave-parallelized:
//   3a: 16 waves = (batch, kc-group) partial-scores MFMA -> PS
//   3b: 1024 threads = one (b,q,k) element: reduce 4 partials, softmax,
//       per-wave 4-q reduce of F*alpha -> WP
//   4 : fused pool+g: one HBF read drives residual-out AND g.
__global__ __launch_bounds__(1024, 4) void attn_main_kernel(
    const float* __restrict__ H, const float* __restrict__ F,
    const unsigned short* __restrict__ Pc,
    float* __restrict__ out, unsigned short* __restrict__ g_ws)
{
    extern __shared__ char smem[];
    char* HBF  = smem;                        // 64 rows x 1024B, swizzled (64 KB)
    char* TBF  = smem + 65536;                // 64 KB
    float* PS  = (float*)(smem + 131072);     // 16 slabs x [16 rows x 17] (17408 B)
    float* WP  = (float*)(smem + 148480);     // [4][4][16] = 1024 B
    float* FL  = (float*)(smem + 149504);     // [64]
    float* LFL = (float*)(smem + 149760);     // [64]

    const int tid = threadIdx.x;
    const int wv = tid >> 6;                  // 0..15
    const int ln = tid & 63;
    const int rl = ln & 15;
    const int kg = ln >> 4;
    const int blk = blockIdx.x;
    const long long gr0 = (long long)blk * 64;
    const float4* hsrc = (const float4*)(H + gr0 * 512);

    float fval = 0.f;
    if (tid < 64) fval = F[blk * 64 + tid];

    float4 hqA[2], hqB[2];
    issue_q(0, tid, hsrc, hqA);

    // per-wave j-slice: j = wv*32 + jj*16 + rl, jj in {0,1}
    const unsigned short* bptr = Pc + ((wv * 32 + rl) * 32 + kg * 8);
    bf16x8 st0[2], st1[2];
    #pragma unroll
    for (int jj = 0; jj < 2; ++jj) st0[jj] = *(const bf16x8*)(bptr + 0 * 16384 + jj * 512);
    #pragma unroll
    for (int jj = 0; jj < 2; ++jj) st1[jj] = *(const bf16x8*)(bptr + 1 * 16384 + jj * 512);

    issue_q(1, tid, hsrc, hqB);

    if (tid < 64) {
        FL[tid] = fval;
        LFL[tid] = logf(fval + 1e-8f);
    }

    f32x4 acc[4][2];
    #pragma unroll
    for (int i = 0; i < 4; ++i)
        #pragma unroll
        for (int jj = 0; jj < 2; ++jj)
            acc[i][jj] = f32x4{0.f, 0.f, 0.f, 0.f};

    convert_q(0, tid, HBF, hqA);
    bar_lgkm();
    gemm_q<true >(0,  tid, rl, kg, bptr, HBF, st0, st1, acc, hqA, hsrc, 2);
    convert_q(1, tid, HBF, hqB);
    bar_lgkm();
    gemm_q<true >(4,  tid, rl, kg, bptr, HBF, st0, st1, acc, hqB, hsrc, 3);
    convert_q(2, tid, HBF, hqA);
    bar_lgkm();
    gemm_q<false>(8,  tid, rl, kg, bptr, HBF, st0, st1, acc, hqA, hsrc, 0);
    convert_q(3, tid, HBF, hqB);
    bar_lgkm();
    gemm_q<false>(12, tid, rl, kg, bptr, HBF, st0, st1, acc, hqB, hsrc, 0);

    // write T into TBF (C layout: col=lane&15, row=(lane>>4)*4+p)
    #pragma unroll
    for (int i = 0; i < 4; ++i)
        #pragma unroll
        for (int jj = 0; jj < 2; ++jj)
            #pragma unroll
            for (int p = 0; p < 4; ++p) {
                unsigned row = (unsigned)(i * 16 + kg * 4 + p);
                unsigned col = (unsigned)(wv * 32 + jj * 16 + rl);
                *(unsigned short*)(TBF + swz1k(row * 1024u + col * 2u)) = f2bf(acc[i][jj][p]);
            }
    bar_lgkm();   // TBF ready

    // ---- phase 3a: partial scores, ALL 16 waves = (batch b, kc-group kcg)
    {
        const int b = wv >> 2, kcg = wv & 3;
        f32x4 sc = f32x4{0.f, 0.f, 0.f, 0.f};
        #pragma unroll
        for (int i = 0; i < 4; ++i) {
            const int kc = kcg * 4 + i;
            unsigned off = (unsigned)(b * 16 + rl) * 1024u + (unsigned)kc * 64u + (unsigned)kg * 16u;
            bf16x8 aT = *(bf16x8*)(TBF + swz1k(off));
            bf16x8 bH = *(bf16x8*)(HBF + swz1k(off));   // H rows as B == H^T
            sc = __builtin_amdgcn_mfma_f32_16x16x32_bf16(aT, bH, sc, 0, 0, 0);
        }
        // PS slab = wv: rows padded to 17 floats (bank-conflict-free)
        float* slab = PS + wv * 272;
        #pragma unroll
        for (int p = 0; p < 4; ++p)
            slab[(kg * 4 + p) * 17 + rl] = sc[p];
    }
    bar_lgkm();   // PS ready

    // ---- phase 3b: flat softmax. thread = (b, q, k)
    {
        const int b = tid >> 8, q = (tid >> 4) & 15, k = tid & 15;
        float s = 0.f;
        #pragma unroll
        for (int g = 0; g < 4; ++g)
            s += PS[(b * 4 + g) * 272 + q * 17 + k];
        s = s * 0.044194173824159216f + LFL[b * 16 + k];   // 1/sqrt(512) + log(F+eps)
        float m = s;
        m = fmaxf(m, __shfl_xor(m, 8));
        m = fmaxf(m, __shfl_xor(m, 4));
        m = fmaxf(m, __shfl_xor(m, 2));
        m = fmaxf(m, __shfl_xor(m, 1));
        float e = expf(s - m);
        float sum = e;
        sum += __shfl_xor(sum, 8);
        sum += __shfl_xor(sum, 4);
        sum += __shfl_xor(sum, 2);
        sum += __shfl_xor(sum, 1);
        float part = FL[b * 16 + q] * (e / sum);
        part += __shfl_xor(part, 16);   // reduce over the wave's 4 q rows
        part += __shfl_xor(part, 32);
        if (ln < 16) WP[(b * 4 + (wv & 3)) * 16 + ln] = part;
    }
    bar_lgkm();   // WP ready

    // ---- phase 4: fused residual pool + g. 16 waves = 4 batches x 4 d-slices.
    {
        const int b = wv >> 2, dq = wv & 3;
        const long long Bg = (long long)blk * 4 + b;
        const int d0 = dq * 128 + ln * 2;                  // 2 cols per lane
        float o0 = 0.f, o1 = 0.f, g0 = 0.f, g1 = 0.f;
        #pragma unroll
        for (int k = 0; k < 16; ++k) {
            unsigned off = (unsigned)(b * 16 + k) * 1024u + (unsigned)d0 * 2u;
            ushort2 h = *(ushort2*)(HBF + swz1k(off));
            float h0 = bf2f(h.x), h1 = bf2f(h.y);
            float fk = FL[b * 16 + k];
            float wk = WP[(b * 4 + 0) * 16 + k] + WP[(b * 4 + 1) * 16 + k]
                     + WP[(b * 4 + 2) * 16 + k] + WP[(b * 4 + 3) * 16 + k];
            o0 = fmaf(fk, h0, o0); o1 = fmaf(fk, h1, o1);
            g0 = fmaf(wk, h0, g0); g1 = fmaf(wk, h1, g1);
        }
        float2 o2; o2.x = o0; o2.y = o1;
        *(float2*)(out + Bg * 512 + d0) = o2;
        ushort2 g2; g2.x = f2bf(g0); g2.y = f2bf(g1);
        *(ushort2*)(g_ws + Bg * 512 + d0) = g2;
    }
}

// ---------------- K3: out += g @ Wv^T   (8192x512 @ 512x512, bf16 MFMA)
__global__ __launch_bounds__(256) void out_gemm_kernel(
    const unsigned short* __restrict__ g_ws,
    const unsigned short* __restrict__ Wvb,
    float* __restrict__ out)
{
    extern __shared__ char smem[];  // 32 KB: 32 rows x 1024B, swizzled
    const int tid = threadIdx.x;
    const int wv = tid >> 6, ln = tid & 63;
    const int rl = ln & 15, kg = ln >> 4;
    const long long r0 = (long long)blockIdx.x * 32;
    {
        const uint4* src = (const uint4*)(g_ws + r0 * 512);
        #pragma unroll
        for (int q = 0; q < 8; ++q) {
            int idx = q * 256 + tid;
            *(uint4*)(smem + swz1k((unsigned)idx * 16u)) = src[idx];
        }
    }
    __syncthreads();
    f32x4 acc[2][8];
    #pragma unroll
    for (int i = 0; i < 2; ++i)
        #pragma unroll
        for (int jj = 0; jj < 8; ++jj)
            acc[i][jj] = f32x4{0.f, 0.f, 0.f, 0.f};
    for (int kc = 0; kc < 16; ++kc) {
        bf16x8 a[2];
        #pragma unroll
        for (int i = 0; i < 2; ++i) {
            unsigned off = (unsigned)(i * 16 + rl) * 1024u + (unsigned)kc * 64u + (unsigned)kg * 16u;
            a[i] = *(bf16x8*)(smem + swz1k(off));
        }
        bf16x8 bfr[8];
        #pragma unroll
        for (int jj = 0; jj < 8; ++jj) {
            int n = wv * 128 + jj * 16 + rl;
            bfr[jj] = *(const bf16x8*)(Wvb + n * 512 + kc * 32 + kg * 8);
        }
        #pragma unroll
        for (int i = 0; i < 2; ++i)
            #pragma unroll
            for (int jj = 0; jj < 8; ++jj)
                acc[i][jj] = __builtin_amdgcn_mfma_f32_16x16x32_bf16(a[i], bfr[jj], acc[i][jj], 0, 0, 0);
    }
    #pragma unroll
    for (int i = 0; i < 2; ++i)
        #pragma unroll
        for (int jj = 0; jj < 8; ++jj)
            #pragma unroll
            for (int p = 0; p < 4; ++p) {
                int row = i * 16 + kg * 4 + p;
                int col = wv * 128 + jj * 16 + rl;
                out[(r0 + row) * 512 + col] += acc[i][jj][p];
            }
}

extern "C" void kernel_launch(void* const* d_in, const int* in_sizes, int n_in,
                              void* d_out, int out_size, void* d_ws, size_t ws_size,
                              hipStream_t stream)
{
    const float* H  = (const float*)d_in[0];
    const float* F  = (const float*)d_in[1];
    const float* Wq = (const float*)d_in[2];
    const float* Wk = (const float*)d_in[3];
    const float* Wv = (const float*)d_in[4];
    float* out = (float*)d_out;

    unsigned short* Pc  = (unsigned short*)d_ws;       // 16*512*32   = 262144 bf16
    unsigned short* Wvb = Pc + 262144;                 // 512*512     = 262144 bf16
    unsigned short* g   = Wvb + 262144;                // 8192*512    = 4194304 bf16
    (void)in_sizes; (void)n_in; (void)out_size; (void)ws_size;

    prep_kernel<<<dim3(2048), dim3(256), 0, stream>>>(Wq, Wk, Wv, Pc, Wvb);
    attn_main_kernel<<<dim3(2048), dim3(1024), 150016, stream>>>(H, F, Pc, out, g);
    out_gemm_kernel<<<dim3(256), dim3(256), 32768, stream>>>(g, Wvb, out);
}